// Round 3
// baseline (452.046 us; speedup 1.0000x reference)
//
#include <hip/hip_runtime.h>
#include <hip/hip_bf16.h>

#define E_MSGS 131072
#define N_NODES 8192
#define D_DIM 256
#define R_MAX 40
#define PW_ELEM 65536          // 256*256 elements per power slot
#define A_STRIDE 260           // fp32 row stride in LDS (mod 32 banks = 4: balanced b128)

typedef __bf16 bf16x8 __attribute__((ext_vector_type(8)));
typedef float f32x4 __attribute__((ext_vector_type(4)));

typedef const __attribute__((address_space(1))) void cg_void;
typedef __attribute__((address_space(3))) void lds_void;

// ================= phase 1: counting sort + segment sort =================

__global__ void k_count(const int* __restrict__ index, int* __restrict__ counts) {
    int e = blockIdx.x * blockDim.x + threadIdx.x;
    if (e < E_MSGS) atomicAdd(&counts[index[e]], 1);
}

// single block: exclusive scan counts->offsets AND count-desc node permutation
__global__ void k_prep(const int* __restrict__ counts, int* __restrict__ offsets,
                       int* __restrict__ perm) {
    __shared__ int partial[256];
    __shared__ int hist[256];
    __shared__ int hscan[256];
    __shared__ int hcur[256];
    int tid = threadIdx.x;
    hist[tid] = 0;
    __syncthreads();

    int base = tid * 32;
    int local[32];
    int sum = 0;
#pragma unroll
    for (int i = 0; i < 32; i++) {
        local[i] = sum;
        int c = counts[base + i];
        sum += c;
        atomicAdd(&hist[min(c, 255)], 1);
    }
    partial[tid] = sum;
    __syncthreads();
    for (int off = 1; off < 256; off <<= 1) {
        int v = (tid >= off) ? partial[tid - off] : 0;
        __syncthreads();
        partial[tid] += v;
        __syncthreads();
    }
    int basesum = (tid > 0) ? partial[tid - 1] : 0;
#pragma unroll
    for (int i = 0; i < 32; i++) offsets[base + i] = basesum + local[i];
    if (tid == 255) offsets[N_NODES] = partial[255];

    hscan[tid] = hist[255 - tid];
    __syncthreads();
    for (int off = 1; off < 256; off <<= 1) {
        int v = (tid >= off) ? hscan[tid - off] : 0;
        __syncthreads();
        hscan[tid] += v;
        __syncthreads();
    }
    hcur[tid] = hscan[255 - tid] - hist[tid];
    __syncthreads();
#pragma unroll
    for (int i = 0; i < 32; i++) {
        int n = base + i;
        int c = min(counts[n], 255);
        int pos = atomicAdd(&hcur[c], 1);
        perm[pos] = n;
    }
}

__global__ void k_scatter(const int* __restrict__ index, const int* __restrict__ offsets,
                          int* __restrict__ cursors, int* __restrict__ bucket) {
    int e = blockIdx.x * blockDim.x + threadIdx.x;
    if (e < E_MSGS) {
        int n = index[e];
        int p = offsets[n] + atomicAdd(&cursors[n], 1);
        bucket[p] = e;
    }
}

// one wave per node: rank segment elements by (t asc, id asc) via shuffles (cnt<=64)
__global__ void k_sortseg(const float* __restrict__ t, const int* __restrict__ offsets,
                          const int* __restrict__ bucket, int* __restrict__ sorted_id) {
    int wid = (blockIdx.x * 256 + threadIdx.x) >> 6;
    int ln = threadIdx.x & 63;
    int beg = offsets[wid], end = offsets[wid + 1];
    int cnt = end - beg;
    int e = 0; float tv = 0.f;
    if (ln < cnt) { e = bucket[beg + ln]; tv = t[e]; }
    int rank = 0;
    for (int j = 0; j < cnt; j++) {
        float tj = __shfl(tv, j);
        int ej = __shfl(e, j);
        rank += (tj < tv) || (tj == tv && ej < e);
    }
    if (ln < cnt) sorted_id[beg + rank] = e;
}

// ================= phase 2: matrix powers =================
// Layouts (bf16, slots 0..R_MAX):
//   Pbrow [r][i][k] = W^r[i][k]   row-major  (A-operand reads, bias)
//   PbrowT[r][j][k] = W^r[k][j]              (B-operand reads in k_pow)
//   pwf   [r]: swizzled B-frag layout for k_gru2 (fully coalesced per (c,t4,w))
//              flat = (((c*4+t4)*4+w)*64 + 16*q + l)*8 + j6, value = W^r[n][k],
//              n = 64w+16t4+l, k = 32c+8q+j6

__global__ void k_pinit(const float* __restrict__ W, __bf16* __restrict__ Pbrow,
                        __bf16* __restrict__ PbrowT, __bf16* __restrict__ pwf) {
    int idx = blockIdx.x * 256 + threadIdx.x;   // 0..65535
    int i = idx >> 8, j = idx & 255;
    __bf16 h = (__bf16)W[idx];
    Pbrow [PW_ELEM + i * 256 + j] = h;
    PbrowT[PW_ELEM + j * 256 + i] = h;
    int c2 = j >> 5, q2 = (j >> 3) & 3, j6 = j & 7;
    int w2 = i >> 6, t42 = (i >> 4) & 3, l2 = i & 15;
    pwf[PW_ELEM + ((((c2 * 4 + t42) * 4 + w2) * 64 + 16 * q2 + l2) * 8 + j6)] = h;
}

// one doubling level: dst = a + pivot for a = 1..batch (grid.x), 64-row tile per grid.y
__global__ void k_pow(const __bf16* __restrict__ Pbrow_r, const __bf16* __restrict__ PbrowT_r,
                      __bf16* __restrict__ Pbrow_w, __bf16* __restrict__ PbrowT_w,
                      __bf16* __restrict__ pwf_w, int pivot) {
    int a = blockIdx.x + 1;
    int dst = pivot + a;
    int rb = blockIdx.y;                 // row tile 0..3
    int tid = threadIdx.x, wave = tid >> 6, lane = tid & 63, q = lane >> 4, l = lane & 15;

    const __bf16* A = Pbrow_r + (size_t)a * PW_ELEM;       // W^a row-major
    const __bf16* B = PbrowT_r + (size_t)pivot * PW_ELEM;  // (W^pivot)^T row-major

    f32x4 acc[4][4];
#pragma unroll
    for (int mt = 0; mt < 4; mt++)
#pragma unroll
        for (int t4 = 0; t4 < 4; t4++) acc[mt][t4] = (f32x4){0.f, 0.f, 0.f, 0.f};

#pragma unroll
    for (int c = 0; c < 8; c++) {
        bf16x8 av[4];
#pragma unroll
        for (int mt = 0; mt < 4; mt++)
            av[mt] = *(const bf16x8*)(A + (64 * rb + 16 * mt + l) * 256 + 32 * c + 8 * q);
#pragma unroll
        for (int t4 = 0; t4 < 4; t4++) {
            bf16x8 bv = *(const bf16x8*)(B + (64 * wave + 16 * t4 + l) * 256 + 32 * c + 8 * q);
#pragma unroll
            for (int mt = 0; mt < 4; mt++)
                acc[mt][t4] = __builtin_amdgcn_mfma_f32_16x16x32_bf16(av[mt], bv, acc[mt][t4], 0, 0, 0);
        }
    }

#pragma unroll
    for (int mt = 0; mt < 4; mt++)
#pragma unroll
        for (int t4 = 0; t4 < 4; t4++)
#pragma unroll
            for (int reg = 0; reg < 4; reg++) {
                int i = 64 * rb + 16 * mt + 4 * q + reg;
                int j = 64 * wave + 16 * t4 + l;
                __bf16 h = (__bf16)acc[mt][t4][reg];
                Pbrow_w [(size_t)dst * PW_ELEM + i * 256 + j] = h;
                PbrowT_w[(size_t)dst * PW_ELEM + j * 256 + i] = h;
                int c2 = j >> 5, q2 = (j >> 3) & 3, j6 = j & 7;
                int w2 = i >> 6, t42 = (i >> 4) & 3, l2 = i & 15;
                pwf_w[(size_t)dst * PW_ELEM +
                      ((((c2 * 4 + t42) * 4 + w2) * 64 + 16 * q2 + l2) * 8 + j6)] = h;
            }
}

// qb[r] = W^r b
__global__ void k_bias(const __bf16* __restrict__ Pbrow, const float* __restrict__ b,
                       float* __restrict__ qb) {
    int r = blockIdx.x + 1;
    int d = threadIdx.x;
    const __bf16* row = Pbrow + (size_t)r * PW_ELEM + d * 256;
    float s = 0.f;
    for (int k = 0; k < 256; k++) s += (float)row[k] * b[k];
    qb[r * 256 + d] = s;
}

// Bp[c] = b + sum_{j=1..c-1} qb[j]  (Bp[0] = 0)
__global__ void k_bprefix(const float* __restrict__ qb, const float* __restrict__ b,
                          float* __restrict__ Bp) {
    int d = threadIdx.x;
    float acc = 0.f;
    Bp[d] = 0.f;
    for (int c = 1; c <= R_MAX; c++) {
        Bp[c * 256 + d] = b[d] + acc;
        acc += qb[c * 256 + d];
    }
}

// ================= phase 3: h[node] = sum_r W^r m_(rev r) + Bp[cnt] =================
// 32 count-sorted nodes/block; steps over r are INDEPENDENT (accumulate in AGPRs).
// A: triple-buffered fp32 LDS via global_load_lds; B: W^r bf16 frags from pwf (L2).

__launch_bounds__(256, 1)
__global__ void k_gru2(const float* __restrict__ msg, const float* __restrict__ zrow,
                       const int* __restrict__ offsets, const int* __restrict__ sorted_id,
                       const int* __restrict__ perm, const __bf16* __restrict__ pwf,
                       const float* __restrict__ Bp, float* __restrict__ out) {
    __shared__ float bufA[3][32 * A_STRIDE];

    int tid = threadIdx.x, wave = tid >> 6, lane = tid & 63, q = lane >> 4, l = lane & 15;
    int node0 = blockIdx.x * 32;

    // gather bookkeeping: wave w stages rows 8w..8w+7
    int off8[8], cnt8[8];
#pragma unroll
    for (int j = 0; j < 8; j++) {
        int n = perm[node0 + 8 * wave + j];
        int o0 = offsets[n], o1 = offsets[n + 1];
        off8[j] = o0; cnt8[j] = o1 - o0;
    }
    int nfirst = perm[node0];                       // global count-desc => first is max
    int S = min(offsets[nfirst + 1] - offsets[nfirst], R_MAX);

    // prologue: DMA A(r=1)->buf1, A(r=2)->buf2
#pragma unroll
    for (int r0 = 1; r0 <= 2; r0++) {
#pragma unroll
        for (int j = 0; j < 8; j++) {
            const float* src = (r0 <= cnt8[j])
                ? msg + (long)sorted_id[off8[j] + cnt8[j] - r0] * D_DIM : zrow;
            float* dst = &bufA[r0 % 3][(8 * wave + j) * A_STRIDE + 4 * lane];
            __builtin_amdgcn_global_load_lds((cg_void*)(src + 4 * lane), (lds_void*)dst, 16, 0, 0);
        }
    }
    // src pointers for r=3
    const float* srcn[8];
#pragma unroll
    for (int j = 0; j < 8; j++)
        srcn[j] = (3 <= cnt8[j]) ? msg + (long)sorted_id[off8[j] + cnt8[j] - 3] * D_DIM : zrow;

    f32x4 acc[2][4];
#pragma unroll
    for (int mt = 0; mt < 2; mt++)
#pragma unroll
        for (int t4 = 0; t4 < 4; t4++) acc[mt][t4] = (f32x4){0.f, 0.f, 0.f, 0.f};
    __syncthreads();

    for (int r = 1; r <= S; r++) {
        // DMA A(r+2) into buf[(r+2)%3] (read two barriers from now)
        if (r + 2 <= S) {
#pragma unroll
            for (int j = 0; j < 8; j++) {
                float* dst = &bufA[(r + 2) % 3][(8 * wave + j) * A_STRIDE + 4 * lane];
                __builtin_amdgcn_global_load_lds((cg_void*)(srcn[j] + 4 * lane), (lds_void*)dst, 16, 0, 0);
            }
        }
        if (r + 3 <= S) {
#pragma unroll
            for (int j = 0; j < 8; j++)
                srcn[j] = (r + 3 <= cnt8[j])
                    ? msg + (long)sorted_id[off8[j] + cnt8[j] - (r + 3)] * D_DIM : zrow;
        }

        const float* A = bufA[r % 3];
        const __bf16* pw = pwf + (size_t)r * PW_ELEM;
#pragma unroll
        for (int c = 0; c < 8; c++) {
            bf16x8 a[2];
#pragma unroll
            for (int mt = 0; mt < 2; mt++) {
                const float* ap = A + (16 * mt + l) * A_STRIDE + 32 * c + 8 * q;
                float4 x0 = *(const float4*)ap;
                float4 x1 = *(const float4*)(ap + 4);
                bf16x8 f;
                f[0] = (__bf16)x0.x; f[1] = (__bf16)x0.y; f[2] = (__bf16)x0.z; f[3] = (__bf16)x0.w;
                f[4] = (__bf16)x1.x; f[5] = (__bf16)x1.y; f[6] = (__bf16)x1.z; f[7] = (__bf16)x1.w;
                a[mt] = f;
            }
#pragma unroll
            for (int t4 = 0; t4 < 4; t4++) {
                bf16x8 bv = *(const bf16x8*)(pw + (((c * 4 + t4) * 4 + wave) * 64 + lane) * 8);
                acc[0][t4] = __builtin_amdgcn_mfma_f32_16x16x32_bf16(a[0], bv, acc[0][t4], 0, 0, 0);
                acc[1][t4] = __builtin_amdgcn_mfma_f32_16x16x32_bf16(a[1], bv, acc[1][t4], 0, 0, 0);
            }
        }
        __syncthreads();
    }

    // epilogue: + Bp[cnt], store fp32
#pragma unroll
    for (int mt = 0; mt < 2; mt++)
#pragma unroll
        for (int reg = 0; reg < 4; reg++) {
            int row = 16 * mt + 4 * q + reg;
            int n = perm[node0 + row];
            int cr = min(offsets[n + 1] - offsets[n], R_MAX);
#pragma unroll
            for (int t4 = 0; t4 < 4; t4++) {
                int col = 64 * wave + 16 * t4 + l;
                out[(long)n * D_DIM + col] = acc[mt][t4][reg] + Bp[cr * 256 + col];
            }
        }
}

// ================= launch =================

extern "C" void kernel_launch(void* const* d_in, const int* in_sizes, int n_in,
                              void* d_out, int out_size, void* d_ws, size_t ws_size,
                              hipStream_t stream) {
    const float* msg   = (const float*)d_in[0];
    const int*   index = (const int*)d_in[1];
    const float* t     = (const float*)d_in[2];
    const float* W     = (const float*)d_in[4];
    const float* b     = (const float*)d_in[5];
    float* out = (float*)d_out;

    int* ws = (int*)d_ws;
    int* counts    = ws;                 // [8192]
    int* cursors   = ws + 8192;          // [8192]
    float* zrow    = (float*)(ws + 16384);  // [256] zeros
    int* offsets   = ws + 16640;         // [8193]
    int* perm      = ws + 24840;         // [8192]
    int* bucket    = ws + 33032;         // [131072]
    int* sorted_id = ws + 164104;        // [131072]

    const size_t FB = 1310720;                         // float/bf16 region base (bytes)
    const size_t PW_BYTES = (size_t)(R_MAX + 1) * PW_ELEM * 2;  // 5,373,952
    char* base = (char*)d_ws;
    __bf16* Pbrow  = (__bf16*)(base + FB);
    __bf16* PbrowT = (__bf16*)(base + FB + PW_BYTES);
    __bf16* pwf    = (__bf16*)(base + FB + 2 * PW_BYTES);
    float*  qb     = (float*)(base + FB + 3 * PW_BYTES);
    float*  Bp     = (float*)(base + FB + 3 * PW_BYTES + (R_MAX + 1) * 256 * 4);

    hipMemsetAsync(counts, 0, 16640 * sizeof(int), stream);  // counts+cursors+zrow

    k_count<<<E_MSGS / 256, 256, 0, stream>>>(index, counts);
    k_prep<<<1, 256, 0, stream>>>(counts, offsets, perm);
    k_scatter<<<E_MSGS / 256, 256, 0, stream>>>(index, offsets, cursors, bucket);
    k_sortseg<<<N_NODES * 64 / 256, 256, 0, stream>>>(t, offsets, bucket, sorted_id);

    k_pinit<<<PW_ELEM / 256, 256, 0, stream>>>(W, Pbrow, PbrowT, pwf);
    const int pivots[6] = {1, 2, 4, 8, 16, 32};
    for (int lv = 0; lv < 6; lv++) {
        int p = pivots[lv];
        int batch = min(p, R_MAX - p);
        k_pow<<<dim3(batch, 4), 256, 0, stream>>>(Pbrow, PbrowT, Pbrow, PbrowT, pwf, p);
    }
    k_bias<<<R_MAX, 256, 0, stream>>>(Pbrow, b, qb);
    k_bprefix<<<1, 256, 0, stream>>>(qb, b, Bp);

    k_gru2<<<N_NODES / 32, 256, 0, stream>>>(msg, zrow, offsets, sorted_id, perm, pwf, Bp, out);
}

// Round 4
// 256.387 us; speedup vs baseline: 1.7631x; 1.7631x over previous
//
#include <hip/hip_runtime.h>
#include <hip/hip_bf16.h>

#define E_MSGS 131072
#define N_NODES 8192
#define D_DIM 256
#define XA_STRIDE 264  // 256 + 8 bf16 pad for A-frag ds_read_b128

typedef __bf16 bf16x8 __attribute__((ext_vector_type(8)));
typedef float f32x4 __attribute__((ext_vector_type(4)));

// raw workgroup barrier: drains LDS (lgkm) only — vmem prefetch stays in flight
#define BAR() asm volatile("s_waitcnt lgkmcnt(0)\n\ts_barrier" ::: "memory")

// ================= phase 1: counting sort + segment sort =================

__global__ void k_count(const int* __restrict__ index, int* __restrict__ counts) {
    int e = blockIdx.x * blockDim.x + threadIdx.x;
    if (e < E_MSGS) atomicAdd(&counts[index[e]], 1);
}

// single block: exclusive scan counts->offsets AND count-desc node permutation
__global__ void k_prep(const int* __restrict__ counts, int* __restrict__ offsets,
                       int* __restrict__ perm) {
    __shared__ int partial[256];
    __shared__ int hist[256];
    __shared__ int hscan[256];
    __shared__ int hcur[256];
    int tid = threadIdx.x;
    hist[tid] = 0;
    __syncthreads();

    int base = tid * 32;
    int local[32];
    int sum = 0;
#pragma unroll
    for (int i = 0; i < 32; i++) {
        local[i] = sum;
        int c = counts[base + i];
        sum += c;
        atomicAdd(&hist[min(c, 255)], 1);
    }
    partial[tid] = sum;
    __syncthreads();
    for (int off = 1; off < 256; off <<= 1) {
        int v = (tid >= off) ? partial[tid - off] : 0;
        __syncthreads();
        partial[tid] += v;
        __syncthreads();
    }
    int basesum = (tid > 0) ? partial[tid - 1] : 0;
#pragma unroll
    for (int i = 0; i < 32; i++) offsets[base + i] = basesum + local[i];
    if (tid == 255) offsets[N_NODES] = partial[255];

    hscan[tid] = hist[255 - tid];
    __syncthreads();
    for (int off = 1; off < 256; off <<= 1) {
        int v = (tid >= off) ? hscan[tid - off] : 0;
        __syncthreads();
        hscan[tid] += v;
        __syncthreads();
    }
    hcur[tid] = hscan[255 - tid] - hist[tid];
    __syncthreads();
#pragma unroll
    for (int i = 0; i < 32; i++) {
        int n = base + i;
        int c = min(counts[n], 255);
        int pos = atomicAdd(&hcur[c], 1);
        perm[pos] = n;
    }
}

__global__ void k_scatter(const int* __restrict__ index, const int* __restrict__ offsets,
                          int* __restrict__ cursors, int* __restrict__ bucket) {
    int e = blockIdx.x * blockDim.x + threadIdx.x;
    if (e < E_MSGS) {
        int n = index[e];
        int p = offsets[n] + atomicAdd(&cursors[n], 1);
        bucket[p] = e;
    }
}

// one wave per node: rank segment elements by (t asc, id asc) via shuffles (cnt<=64)
__global__ void k_sortseg(const float* __restrict__ t, const int* __restrict__ offsets,
                          const int* __restrict__ bucket, int* __restrict__ sorted_id) {
    int wid = (blockIdx.x * 256 + threadIdx.x) >> 6;
    int ln = threadIdx.x & 63;
    int beg = offsets[wid], end = offsets[wid + 1];
    int cnt = end - beg;
    int e = 0; float tv = 0.f;
    if (ln < cnt) { e = bucket[beg + ln]; tv = t[e]; }
    int rank = 0;
    for (int j = 0; j < cnt; j++) {
        float tj = __shfl(tv, j);
        int ej = __shfl(e, j);
        rank += (tj < tv) || (tj == tv && ej < e);
    }
    if (ln < cnt) sorted_id[beg + rank] = e;
}

// ================= phase 2: serial recurrence, raw barriers, reg prefetch =======
// 16 count-grouped nodes/block. W (bf16) entirely in registers (wave owns 64
// out-dims). h fp32 in regs. x=(m+h) round-trips LDS bf16. msg prefetched 2 steps
// ahead into REGISTERS (per-lane loads); barrier = raw s_barrier + lgkm drain only,
// so the vmem prefetch is never drained by the per-step barrier.

__launch_bounds__(256, 2)
__global__ void k_gru(const float* __restrict__ msg, const float* __restrict__ W,
                      const float* __restrict__ b, const int* __restrict__ offsets,
                      const int* __restrict__ sorted_id, const int* __restrict__ perm,
                      float* __restrict__ out) {
    __shared__ __bf16 xA[2][16 * XA_STRIDE];

    int tid  = threadIdx.x;
    int wave = tid >> 6;
    int lane = tid & 63;
    int q    = lane >> 4;
    int l    = lane & 15;
    int node0 = blockIdx.x * 16;

    // ---- W fragments (B operand: B[k][n]=W[n][k]; lane n=64w+16t4+l, k=32c+8q+j) ----
    bf16x8 wf[8][4];
#pragma unroll
    for (int t4 = 0; t4 < 4; t4++) {
        const float* wr = W + (64 * wave + 16 * t4 + l) * D_DIM;
#pragma unroll
        for (int c = 0; c < 8; c++) {
            int k0 = 32 * c + 8 * q;
            float4 w0 = *(const float4*)(wr + k0);
            float4 w1 = *(const float4*)(wr + k0 + 4);
            bf16x8 f;
            f[0] = (__bf16)w0.x; f[1] = (__bf16)w0.y; f[2] = (__bf16)w0.z; f[3] = (__bf16)w0.w;
            f[4] = (__bf16)w1.x; f[5] = (__bf16)w1.y; f[6] = (__bf16)w1.z; f[7] = (__bf16)w1.w;
            wf[c][t4] = f;
        }
    }
    float bias[4];
#pragma unroll
    for (int t4 = 0; t4 < 4; t4++) bias[t4] = b[64 * wave + 16 * t4 + l];

    // quad q owns C/D rows 4q+r
    int nodeC[4], off4[4], cnt4[4];
#pragma unroll
    for (int r = 0; r < 4; r++) {
        int n = perm[node0 + 4 * q + r];
        nodeC[r] = n;
        off4[r] = offsets[n];
        cnt4[r] = offsets[n + 1] - off4[r];
    }
    int nfirst = perm[node0];  // count-desc perm: first node has block max
    int S = offsets[nfirst + 1] - offsets[nfirst];

    float h[4][4];
#pragma unroll
    for (int t4 = 0; t4 < 4; t4++)
#pragma unroll
        for (int r = 0; r < 4; r++) h[t4][r] = 0.f;

    // ---- prologue: x_0 = m_0; mvA = m_1; sidp = sid(m_2) ----
    float mvA[4][4], mvB[4][4];
    int sidp[4];
#pragma unroll
    for (int r = 0; r < 4; r++) {
        int sid0 = sorted_id[min(off4[r], E_MSGS - 1)];
        int sid1 = sorted_id[min(off4[r] + 1, E_MSGS - 1)];
        const float* m0 = msg + (long)sid0 * D_DIM;
        const float* m1 = msg + (long)sid1 * D_DIM;
#pragma unroll
        for (int t4 = 0; t4 < 4; t4++) {
            int col = 64 * wave + 16 * t4 + l;
            xA[0][(4 * q + r) * XA_STRIDE + col] = (__bf16)m0[col];
            mvA[r][t4] = m1[col];
        }
        sidp[r] = sorted_id[min(off4[r] + 2, E_MSGS - 1)];
    }
    BAR();

    // one step: consume cur (=m_{s+1}) in epilogue, prefetch m_{s+2} into nxt
    auto step = [&](int s, float (&cur)[4][4], float (&nxt)[4][4]) {
        // prefetch m_{s+2} (register loads — survive the barrier)
#pragma unroll
        for (int r = 0; r < 4; r++) {
            const float* mrow = msg + (long)sidp[r] * D_DIM;
#pragma unroll
            for (int t4 = 0; t4 < 4; t4++) nxt[r][t4] = mrow[64 * wave + 16 * t4 + l];
        }
#pragma unroll
        for (int r = 0; r < 4; r++)
            sidp[r] = sorted_id[min(off4[r] + s + 3, E_MSGS - 1)];

        // MFMA: acc = x_s @ W^T
        const __bf16* buf = xA[s & 1];
        f32x4 acc[4];
#pragma unroll
        for (int t4 = 0; t4 < 4; t4++) acc[t4] = (f32x4){0.f, 0.f, 0.f, 0.f};
#pragma unroll
        for (int c = 0; c < 8; c++) {
            bf16x8 a = *(const bf16x8*)(buf + l * XA_STRIDE + 32 * c + 8 * q);
#pragma unroll
            for (int t4 = 0; t4 < 4; t4++)
                acc[t4] = __builtin_amdgcn_mfma_f32_16x16x32_bf16(a, wf[c][t4], acc[t4], 0, 0, 0);
        }

        // epilogue: h update (masked) + x_{s+1} = h + m_{s+1}
        __bf16* nbuf = xA[(s + 1) & 1];
#pragma unroll
        for (int t4 = 0; t4 < 4; t4++) {
#pragma unroll
            for (int r = 0; r < 4; r++) {
                float hn = acc[t4][r] + bias[t4];
                bool valid = s < cnt4[r];
                h[t4][r] = valid ? hn : h[t4][r];
                nbuf[(4 * q + r) * XA_STRIDE + 64 * wave + 16 * t4 + l] =
                    (__bf16)(h[t4][r] + cur[r][t4]);
            }
        }
        BAR();
    };

    int s = 0;
    while (s < S) {
        step(s, mvA, mvB);
        s++;
        if (s >= S) break;
        step(s, mvB, mvA);
        s++;
    }

    // ---- write fp32 h (0 for empty nodes) ----
#pragma unroll
    for (int t4 = 0; t4 < 4; t4++)
#pragma unroll
        for (int r = 0; r < 4; r++)
            out[(long)nodeC[r] * D_DIM + 64 * wave + 16 * t4 + l] = h[t4][r];
}

// ================= launch =================

extern "C" void kernel_launch(void* const* d_in, const int* in_sizes, int n_in,
                              void* d_out, int out_size, void* d_ws, size_t ws_size,
                              hipStream_t stream) {
    const float* msg   = (const float*)d_in[0];
    const int*   index = (const int*)d_in[1];
    const float* t     = (const float*)d_in[2];
    const float* W     = (const float*)d_in[4];
    const float* b     = (const float*)d_in[5];
    float* out = (float*)d_out;

    int* ws = (int*)d_ws;
    int* counts    = ws;                // [8192]
    int* cursors   = ws + 8192;         // [8192]
    int* offsets   = ws + 16384;        // [8193]
    int* perm      = ws + 24584;        // [8192]
    int* bucket    = ws + 32776;        // [131072]
    int* sorted_id = ws + 163848;       // [131072]

    hipMemsetAsync(counts, 0, 16384 * sizeof(int), stream);  // counts + cursors

    k_count<<<E_MSGS / 256, 256, 0, stream>>>(index, counts);
    k_prep<<<1, 256, 0, stream>>>(counts, offsets, perm);
    k_scatter<<<E_MSGS / 256, 256, 0, stream>>>(index, offsets, cursors, bucket);
    k_sortseg<<<N_NODES * 64 / 256, 256, 0, stream>>>(t, offsets, bucket, sorted_id);
    k_gru<<<N_NODES / 16, 256, 0, stream>>>(msg, W, b, offsets, sorted_id, perm, out);
}